// Round 4
// baseline (564.162 us; speedup 1.0000x reference)
//
#include <hip/hip_runtime.h>
#include <cstdint>
#include <cstddef>

typedef float    f32x16 __attribute__((ext_vector_type(16)));
typedef __bf16   bf16x8 __attribute__((ext_vector_type(8)));
typedef unsigned u32x2  __attribute__((ext_vector_type(2)));
typedef unsigned u32x4  __attribute__((ext_vector_type(4)));

static_assert(sizeof(bf16x8) == 16, "bf16x8 must be 16B");

#define DEV __device__ __forceinline__

// round-to-nearest-even float -> bf16 bits
DEV unsigned f2bf_bits(float f) {
    unsigned u = __builtin_bit_cast(unsigned, f);
    return ((u + 0x7fffu + ((u >> 16) & 1u)) >> 16) & 0xffffu;
}
DEV float bf2f(unsigned bits) {
    return __builtin_bit_cast(float, bits << 16);
}
DEV unsigned pack2(float a, float b) {
    return f2bf_bits(a) | (f2bf_bits(b) << 16);
}

constexpr int D     = 64;
constexpr int SLEN  = 4096;
constexpr int KBLK  = 128;   // semantic block size (must match reference BLOCK_SIZE)
constexpr int NBLK  = SLEN / KBLK;
constexpr int QTILE = 128;   // 4 waves * 32 q-rows
constexpr int VSTR  = 136;   // V^T row stride in elems (272B, 16B-aligned, conflict-benign)

__global__ __launch_bounds__(256, 2)
void fa_fwd(const float* __restrict__ Qg, const float* __restrict__ Kg,
            const float* __restrict__ Vg, float* __restrict__ Og)
{
    // K staged as bf16 hi/lo in frag-linear layout: chunk (ki*4+c)*64 + lane,
    // each chunk = 8 consecutive d of one k-row -> ds_read_b128, conflict-free.
    __shared__ __align__(16) unsigned short khi[KBLK * D];
    __shared__ __align__(16) unsigned short klo[KBLK * D];
    // V^T staged bf16: vt[d * VSTR + kv]  (row-major in d, 8 consecutive kv per b128 read)
    __shared__ __align__(16) unsigned short vt[D * VSTR];

    const int tid = threadIdx.x;
    const int l   = tid & 63;
    const int w   = tid >> 6;
    const int h   = l >> 5;    // lane half
    const int ln  = l & 31;

    const int  bh   = blockIdx.y;
    const long base = (long)bh * SLEN * D;
    const float* Qb = Qg + base;
    const float* Kb = Kg + base;
    const float* Vb = Vg + base;
    float*       Ob = Og + base;

    // ---- load Q fragments (B-operand of S^T = K·Q^T), scale 1/8 folded, hi/lo split
    const int qrow = blockIdx.x * QTILE + w * 32 + ln;
    bf16x8 qhi[4], qlo[4];
#pragma unroll
    for (int c = 0; c < 4; ++c) {
        const float* qp = Qb + (long)qrow * D + c * 16 + h * 8;
        float4 x0 = *(const float4*)qp;
        float4 x1 = *(const float4*)(qp + 4);
        float xs[8] = {x0.x, x0.y, x0.z, x0.w, x1.x, x1.y, x1.z, x1.w};
        unsigned hw[4], lw[4];
#pragma unroll
        for (int j = 0; j < 4; ++j) {
            float a = xs[2 * j] * 0.125f, b = xs[2 * j + 1] * 0.125f;
            unsigned ha = f2bf_bits(a), hb = f2bf_bits(b);
            lw[j] = f2bf_bits(a - bf2f(ha)) | (f2bf_bits(b - bf2f(hb)) << 16);
            hw[j] = ha | (hb << 16);
        }
        u32x4 H = {hw[0], hw[1], hw[2], hw[3]};
        u32x4 L = {lw[0], lw[1], lw[2], lw[3]};
        qhi[c] = __builtin_bit_cast(bf16x8, H);
        qlo[c] = __builtin_bit_cast(bf16x8, L);
    }

    f32x16 oa0 = {};   // O^T tile dj=0 (d = 0..31 rows, q = lane&31 col)
    f32x16 oa1 = {};   // O^T tile dj=1 (d = 32..63)
    f32x16 st[4];      // S^T tiles, becomes P after exp

    float mrun = -INFINITY;
    float norm = 0.0f;

    const int e  = tid & 3;           // quad element for V transpose
    const int e0 = e & 1, e1 = e >> 1;
    const int DQi = (tid >> 2) & 15;  // per-wave: d-quad index 0..15

#pragma unroll 1
    for (int kb = 0; kb < NBLK; ++kb) {
        const int kv0 = kb * KBLK;

        // ---- stage K (hi/lo, frag-linear) ----
#pragma unroll
        for (int i = 0; i < 4; ++i) {
            int chunk = i * 256 + tid;            // [0,1024)
            int ki  = chunk >> 8;
            int c   = (chunk >> 6) & 3;
            int cl  = chunk & 63;
            int row = ki * 32 + (cl & 31);
            int d0  = c * 16 + (cl >> 5) * 8;
            const float* kp = Kb + (long)(kv0 + row) * D + d0;
            float4 x0 = *(const float4*)kp;
            float4 x1 = *(const float4*)(kp + 4);
            float xs[8] = {x0.x, x0.y, x0.z, x0.w, x1.x, x1.y, x1.z, x1.w};
            unsigned hw[4], lw[4];
#pragma unroll
            for (int j = 0; j < 4; ++j) {
                float a = xs[2 * j], b = xs[2 * j + 1];
                unsigned ha = f2bf_bits(a), hb = f2bf_bits(b);
                lw[j] = f2bf_bits(a - bf2f(ha)) | (f2bf_bits(b - bf2f(hb)) << 16);
                hw[j] = ha | (hb << 16);
            }
            u32x4 H = {hw[0], hw[1], hw[2], hw[3]};
            u32x4 L = {lw[0], lw[1], lw[2], lw[3]};
            *(u32x4*)&khi[chunk * 8] = H;
            *(u32x4*)&klo[chunk * 8] = L;
        }

        // ---- stage V^T (bf16) via in-register 4x4 quad transpose ----
        // lane quad (KQ,DQ): lane e loads V[KQ+e][DQ..DQ+3], transposes to
        // V[KQ..KQ+3][DQ+e], writes one ds_write_b64 row-segment of vt.
#pragma unroll
        for (int i = 0; i < 8; ++i) {
            int KQ = (i * 4 + w) * 4;             // kv-quad base, covers 0..124
            int DQ = DQi * 4;                     // d-quad base, covers 0..60
            float4 x = *(const float4*)(Vb + (long)(kv0 + KQ + e) * D + DQ);
            float f0 = x.x, f1 = x.y, f2 = x.z, f3 = x.w;
            // phase A: swap bit0 of (row,col) within lane pairs
            float sA0 = e0 ? f0 : f1, sA1 = e0 ? f2 : f3;
            float rA0 = __shfl_xor(sA0, 1, 64), rA1 = __shfl_xor(sA1, 1, 64);
            float A0 = e0 ? rA0 : f0, A1 = e0 ? f1 : rA0;
            float A2 = e0 ? rA1 : f2, A3 = e0 ? f3 : rA1;
            // phase B: swap bit1 within lane pairs-of-pairs
            float sB0 = e1 ? A0 : A2, sB1 = e1 ? A1 : A3;
            float rB0 = __shfl_xor(sB0, 2, 64), rB1 = __shfl_xor(sB1, 2, 64);
            float B0 = e1 ? rB0 : A0, B1 = e1 ? rB1 : A1;
            float B2 = e1 ? A2 : rB0, B3 = e1 ? A3 : rB1;
            // now B_i = V[KQ+i][DQ+e]
            u32x2 p;
            p.x = pack2(B0, B1);
            p.y = pack2(B2, B3);
            *(u32x2*)&vt[(DQ + e) * VSTR + KQ] = p;
        }

        __syncthreads();

        // ---- S^T = K · Q^T, 3-term bf16 split (≈ fp32 scores) ----
#pragma unroll
        for (int ki = 0; ki < 4; ++ki) {
            f32x16 acc = {};
#pragma unroll
            for (int c = 0; c < 4; ++c) {
                int ch = (ki * 4 + c) * 64 + l;
                bf16x8 ah = *(const bf16x8*)&khi[ch * 8];
                bf16x8 al = *(const bf16x8*)&klo[ch * 8];
                acc = __builtin_amdgcn_mfma_f32_32x32x16_bf16(ah, qhi[c], acc, 0, 0, 0);
                acc = __builtin_amdgcn_mfma_f32_32x32x16_bf16(ah, qlo[c], acc, 0, 0, 0);
                acc = __builtin_amdgcn_mfma_f32_32x32x16_bf16(al, qhi[c], acc, 0, 0, 0);
            }
            st[ki] = acc;
        }

        // ---- softmax (reference's exact recurrence: exp(s - block_max)) ----
        float bm = -INFINITY;
#pragma unroll
        for (int ki = 0; ki < 4; ++ki)
#pragma unroll
            for (int r = 0; r < 16; ++r) bm = fmaxf(bm, st[ki][r]);
        bm = fmaxf(bm, __shfl_xor(bm, 32, 64));   // block max over all 128 kv

        float newm = fmaxf(mrun, bm);
        float sc   = __expf(mrun - newm);         // first block: exp(-inf) = 0
        mrun = newm;

        float psum = 0.0f;
#pragma unroll
        for (int ki = 0; ki < 4; ++ki) {
#pragma unroll
            for (int r = 0; r < 16; ++r) {
                float p = __expf(st[ki][r] - bm);
                st[ki][r] = p;
                psum += p;
            }
        }
        psum += __shfl_xor(psum, 32, 64);
        norm = norm * sc + psum;

#pragma unroll
        for (int r = 0; r < 16; ++r) { oa0[r] *= sc; oa1[r] *= sc; }

        // ---- build P^T fragments (half-swap across lane 32 boundary) ----
        bf16x8 pf[8];
#pragma unroll
        for (int c = 0; c < 8; ++c) {
            int ki = c >> 1, half = c & 1;
            int rb = half * 8;
            unsigned A0 = pack2(st[ki][rb + 0], st[ki][rb + 1]);
            unsigned A1 = pack2(st[ki][rb + 2], st[ki][rb + 3]);
            unsigned B0 = pack2(st[ki][rb + 4], st[ki][rb + 5]);
            unsigned B1 = pack2(st[ki][rb + 6], st[ki][rb + 7]);
            unsigned s0 = h ? A0 : B0;
            unsigned s1 = h ? A1 : B1;
            unsigned r0 = (unsigned)__shfl_xor((int)s0, 32, 64);
            unsigned r1 = (unsigned)__shfl_xor((int)s1, 32, 64);
            u32x4 f;
            f.x = h ? r0 : A0;
            f.y = h ? r1 : A1;
            f.z = h ? B0 : r0;
            f.w = h ? B1 : r1;
            pf[c] = __builtin_bit_cast(bf16x8, f);
        }

        // ---- O^T += V^T · P^T  (V^T fragments via plain ds_read_b128) ----
#pragma unroll
        for (int c = 0; c < 8; ++c) {
            const int kvo = c * 16 + h * 8;
            bf16x8 va = *(const bf16x8*)&vt[(ln)      * VSTR + kvo];
            bf16x8 vb = *(const bf16x8*)&vt[(32 + ln) * VSTR + kvo];
            oa0 = __builtin_amdgcn_mfma_f32_32x32x16_bf16(va, pf[c], oa0, 0, 0, 0);
            oa1 = __builtin_amdgcn_mfma_f32_32x32x16_bf16(vb, pf[c], oa1, 0, 0, 0);
        }

        __syncthreads();
    }

    // ---- epilogue: O = O^T / (norm + 1e-6) ----
    float inv = 1.0f / (norm + 1e-6f);
    long  orow = (long)qrow * D;
#pragma unroll
    for (int rg = 0; rg < 4; ++rg) {
        int d0 = 8 * rg + 4 * h;
        float4 w0, w1;
        w0.x = oa0[4 * rg + 0] * inv;
        w0.y = oa0[4 * rg + 1] * inv;
        w0.z = oa0[4 * rg + 2] * inv;
        w0.w = oa0[4 * rg + 3] * inv;
        w1.x = oa1[4 * rg + 0] * inv;
        w1.y = oa1[4 * rg + 1] * inv;
        w1.z = oa1[4 * rg + 2] * inv;
        w1.w = oa1[4 * rg + 3] * inv;
        *(float4*)(Ob + orow + d0)      = w0;
        *(float4*)(Ob + orow + 32 + d0) = w1;
    }
}

extern "C" void kernel_launch(void* const* d_in, const int* in_sizes, int n_in,
                              void* d_out, int out_size, void* d_ws, size_t ws_size,
                              hipStream_t stream)
{
    (void)in_sizes; (void)n_in; (void)d_ws; (void)ws_size; (void)out_size;
    const float* q = (const float*)d_in[0];
    const float* k = (const float*)d_in[1];
    const float* v = (const float*)d_in[2];
    float*       o = (float*)d_out;

    dim3 grid(SLEN / QTILE, 2 * 16);   // (32 q-tiles, B*H) — x-fast keeps same-bh blocks adjacent for L2
    dim3 block(256);
    hipLaunchKernelGGL(fa_fwd, grid, block, 0, stream, q, k, v, o);
}